// Round 16
// baseline (37.402 us; speedup 1.0000x reference)
//
#include <hip/hip_runtime.h>

#define Bn 1024
#define Pn 128
#define Fn 512
#define Dn 256
#define THETA 1e-7f

typedef _Float16 f16;
typedef f16 f16x8 __attribute__((ext_vector_type(8)));
typedef f16 f16x4 __attribute__((ext_vector_type(4)));
typedef f16 f16x2 __attribute__((ext_vector_type(2)));
typedef float f32x4 __attribute__((ext_vector_type(4)));

// ---------------------------------------------------------------------------
// K1: exact f32 GEMM [x; prototypes] @ fb^T (round-1 body, proven).
// Epilogue (round-8 version, proven): f16 relu values + 0/1 masks, masks
// computed from EXACT f32 sign. All row-major [row][Fn]:
//   rows <  Bn -> RX, BX ;  rows >= Bn -> RP, BP
// ---------------------------------------------------------------------------
__global__ __launch_bounds__(256)
void gemm_feat(const float* __restrict__ x, const float* __restrict__ prot,
               const float* __restrict__ fb,
               f16* __restrict__ RX, f16* __restrict__ BX,
               f16* __restrict__ RP, f16* __restrict__ BP)
{
    __shared__ float As[64][68];
    __shared__ float Fs[64][68];
    const int tid = threadIdx.x;
    const int rb  = blockIdx.y * 64;
    const int cb  = blockIdx.x * 64;
    const int tx  = tid & 15;
    const int ty  = tid >> 4;
    const int lr  = tid >> 2;
    const int lk  = tid & 3;

    float acc[4][4] = {};

    for (int k0 = 0; k0 < Dn; k0 += 64) {
        #pragma unroll
        for (int q = 0; q < 4; ++q) {
            const int kk = lk + q * 4;
            const int r  = rb + lr;
            const float* asrc = (r < Bn) ? (x + (size_t)r * Dn)
                                         : (prot + (size_t)(r - Bn) * Dn);
            float4 av = *(const float4*)(asrc + k0 + kk * 4);
            float4 fv = *(const float4*)(fb + (size_t)(cb + lr) * Dn + k0 + kk * 4);
            As[kk*4+0][lr] = av.x; As[kk*4+1][lr] = av.y;
            As[kk*4+2][lr] = av.z; As[kk*4+3][lr] = av.w;
            Fs[kk*4+0][lr] = fv.x; Fs[kk*4+1][lr] = fv.y;
            Fs[kk*4+2][lr] = fv.z; Fs[kk*4+3][lr] = fv.w;
        }
        __syncthreads();
        #pragma unroll 8
        for (int k = 0; k < 64; ++k) {
            float4 a = *(const float4*)&As[k][ty * 4];
            float4 f = *(const float4*)&Fs[k][tx * 4];
            const float aa[4] = {a.x, a.y, a.z, a.w};
            const float ff[4] = {f.x, f.y, f.z, f.w};
            #pragma unroll
            for (int i = 0; i < 4; ++i)
                #pragma unroll
                for (int j = 0; j < 4; ++j)
                    acc[i][j] = fmaf(aa[i], ff[j], acc[i][j]);
        }
        __syncthreads();
    }

    #pragma unroll
    for (int i = 0; i < 4; ++i) {
        const int r = rb + ty * 4 + i;
        f16x4 rv, bv;
        #pragma unroll
        for (int j = 0; j < 4; ++j) {
            const float v = acc[i][j];
            rv[j] = (f16)fmaxf(v, 0.f);
            bv[j] = (v > 0.f) ? (f16)1 : (f16)0;
        }
        f16 *rd, *bd;
        size_t off;
        if (r < Bn) { rd = RX; bd = BX; off = (size_t)r * Fn + cb + tx * 4; }
        else        { rd = RP; bd = BP; off = (size_t)(r - Bn) * Fn + cb + tx * 4; }
        *(f16x4*)(rd + off) = rv;
        *(f16x4*)(bd + off) = bv;
    }
}

// ---------------------------------------------------------------------------
// K2 v7: MFMA for I/X/P, packed VALU only for M.
//  Block = 16b x 16p output tile, 4 waves; wave w owns F-quarter w (128 f).
//  Phase A (MFMA, round-8 validated layouts): per k-step (32 f):
//    A-frag row=l&15, k=(l>>4)*8 from RX/BX; B-frag col=l&15 from RP/BP;
//    aI = mfma(rx,rp,aI); aX = mfma(rx,bp,aX); aP = mfma(bx,rp,aP).
//    C/D: col=l&15, row=(l>>4)*4+i.
//  Phase B (M): lane l covers b_local=l>>2, p_local=(l&3)*4+j (j=0..3);
//    f16x2 min/add accumulators, flushed to f32 every 16 f (v6 cadence).
//  Phase C: LDS combine of 4 wave-partials (deterministic) + ratio.
//  Grid (Bn/16, Pn/16) = 64 x 8 = 512 blocks; LDS 16 KB.
// ---------------------------------------------------------------------------
__global__ __launch_bounds__(256)
void tversky_main(const f16* __restrict__ RX, const f16* __restrict__ BX,
                  const f16* __restrict__ RP, const f16* __restrict__ BP,
                  const float* __restrict__ alpha_p, const float* __restrict__ beta_p,
                  float* __restrict__ out)
{
    __shared__ float sI[4][256], sX[4][256], sP[4][256], sM[4][256];
    const int tid  = threadIdx.x;
    const int w    = tid >> 6;           // wave = F-quarter
    const int lane = tid & 63;
    const int bb   = blockIdx.x * 16;
    const int pb   = blockIdx.y * 16;
    const int f0   = w * 128;

    // ---------------- Phase A: MFMA over F-quarter ----------------
    {
        const size_t abase = (size_t)(bb + (lane & 15)) * Fn + f0 + (lane >> 4) * 8;
        const size_t bbase = (size_t)(pb + (lane & 15)) * Fn + f0 + (lane >> 4) * 8;
        f32x4 aI = {}, aX = {}, aP = {};
        #pragma unroll
        for (int ks = 0; ks < 4; ++ks) {
            const f16x8 rx = *(const f16x8*)(RX + abase + ks * 32);
            const f16x8 bx = *(const f16x8*)(BX + abase + ks * 32);
            const f16x8 rp = *(const f16x8*)(RP + bbase + ks * 32);
            const f16x8 bp = *(const f16x8*)(BP + bbase + ks * 32);
            aI = __builtin_amdgcn_mfma_f32_16x16x32_f16(rx, rp, aI, 0, 0, 0);
            aX = __builtin_amdgcn_mfma_f32_16x16x32_f16(rx, bp, aX, 0, 0, 0);
            aP = __builtin_amdgcn_mfma_f32_16x16x32_f16(bx, rp, aP, 0, 0, 0);
        }
        #pragma unroll
        for (int i = 0; i < 4; ++i) {
            const int idx = ((lane >> 4) * 4 + i) * 16 + (lane & 15);
            sI[w][idx] = aI[i]; sX[w][idx] = aX[i]; sP[w][idx] = aP[i];
        }
    }

    // ---------------- Phase B: M = sum min(rx, rp) over F-quarter ----------
    {
        const int bl = lane >> 2;            // b_local 0..15
        const int pg = lane & 3;             // p-group (4 p's)
        const f16* xrow = RX + (size_t)(bb + bl) * Fn + f0;
        const f16* prow0 = RP + (size_t)(pb + pg * 4) * Fn + f0;

        float fM[4] = {};
        #pragma unroll
        for (int ep = 0; ep < 8; ++ep) {     // 8 epochs x 16 f = 128 f
            f16x2 aM[4] = {};
            #pragma unroll
            for (int gg = 0; gg < 2; ++gg) {
                const int g = ep * 2 + gg;
                const f16x8 rx = *(const f16x8*)(xrow + g * 8);
                #pragma unroll
                for (int j = 0; j < 4; ++j) {
                    const f16x8 rp = *(const f16x8*)(prow0 + (size_t)j * Fn + g * 8);
                    const f16x8 mn = __builtin_elementwise_min(rx, rp);
                    const f16x4 ml = mn.lo, mh = mn.hi;
                    aM[j] = aM[j] + ml.lo;
                    aM[j] = aM[j] + ml.hi;
                    aM[j] = aM[j] + mh.lo;
                    aM[j] = aM[j] + mh.hi;
                }
            }
            #pragma unroll
            for (int j = 0; j < 4; ++j)
                fM[j] += (float)aM[j][0] + (float)aM[j][1];
        }
        #pragma unroll
        for (int j = 0; j < 4; ++j)
            sM[w][bl * 16 + pg * 4 + j] = fM[j];
    }

    __syncthreads();

    // ---------------- Phase C: combine + ratio ----------------
    {
        float I = 0.f, X = 0.f, P = 0.f, M = 0.f;
        #pragma unroll
        for (int s = 0; s < 4; ++s) {
            I += sI[s][tid]; X += sX[s][tid]; P += sP[s][tid]; M += sM[s][tid];
        }
        const float alpha = *alpha_p;
        const float beta  = *beta_p;
        const float W = alpha * (X - M) + beta * (P - M);
        out[(size_t)(bb + (tid >> 4)) * Pn + pb + (tid & 15)] = I / (I + W + THETA);
    }
}

extern "C" void kernel_launch(void* const* d_in, const int* in_sizes, int n_in,
                              void* d_out, int out_size, void* d_ws, size_t ws_size,
                              hipStream_t stream)
{
    const float* x     = (const float*)d_in[0];
    const float* prot  = (const float*)d_in[1];
    const float* fb    = (const float*)d_in[2];
    const float* alpha = (const float*)d_in[3];
    const float* beta  = (const float*)d_in[4];
    float* out = (float*)d_out;

    f16* RX = (f16*)d_ws;                    // Bn*Fn f16
    f16* BX = RX + (size_t)Bn * Fn;          // Bn*Fn f16
    f16* RP = BX + (size_t)Bn * Fn;          // Pn*Fn f16
    f16* BP = RP + (size_t)Pn * Fn;          // Pn*Fn f16

    dim3 gg(Fn / 64, (Bn + Pn) / 64);        // 8 x 18 = 144 blocks
    gemm_feat<<<gg, 256, 0, stream>>>(x, prot, fb, RX, BX, RP, BP);

    dim3 gm(Bn / 16, Pn / 16);               // 64 x 8 = 512 blocks
    tversky_main<<<gm, 256, 0, stream>>>(RX, BX, RP, BP, alpha, beta, out);
}

// Round 17
// 37.330 us; speedup vs baseline: 1.0019x; 1.0019x over previous
//
#include <hip/hip_runtime.h>

#define Bn 1024
#define Pn 128
#define Fn 512
#define Dn 256
#define THETA 1e-7f

typedef _Float16 f16;
typedef f16 f16x8 __attribute__((ext_vector_type(8)));
typedef f16 f16x4 __attribute__((ext_vector_type(4)));
typedef f16 f16x2 __attribute__((ext_vector_type(2)));
typedef float f32x4 __attribute__((ext_vector_type(4)));

// ---------------------------------------------------------------------------
// K1: exact f32 GEMM [x; prototypes] @ fb^T (round-1 body, proven).
// Epilogue (round-8 version, proven): f16 relu values + 0/1 masks, masks
// computed from EXACT f32 sign. All row-major [row][Fn]:
//   rows <  Bn -> RX, BX ;  rows >= Bn -> RP, BP
// ---------------------------------------------------------------------------
__global__ __launch_bounds__(256)
void gemm_feat(const float* __restrict__ x, const float* __restrict__ prot,
               const float* __restrict__ fb,
               f16* __restrict__ RX, f16* __restrict__ BX,
               f16* __restrict__ RP, f16* __restrict__ BP)
{
    __shared__ float As[64][68];
    __shared__ float Fs[64][68];
    const int tid = threadIdx.x;
    const int rb  = blockIdx.y * 64;
    const int cb  = blockIdx.x * 64;
    const int tx  = tid & 15;
    const int ty  = tid >> 4;
    const int lr  = tid >> 2;
    const int lk  = tid & 3;

    float acc[4][4] = {};

    for (int k0 = 0; k0 < Dn; k0 += 64) {
        #pragma unroll
        for (int q = 0; q < 4; ++q) {
            const int kk = lk + q * 4;
            const int r  = rb + lr;
            const float* asrc = (r < Bn) ? (x + (size_t)r * Dn)
                                         : (prot + (size_t)(r - Bn) * Dn);
            float4 av = *(const float4*)(asrc + k0 + kk * 4);
            float4 fv = *(const float4*)(fb + (size_t)(cb + lr) * Dn + k0 + kk * 4);
            As[kk*4+0][lr] = av.x; As[kk*4+1][lr] = av.y;
            As[kk*4+2][lr] = av.z; As[kk*4+3][lr] = av.w;
            Fs[kk*4+0][lr] = fv.x; Fs[kk*4+1][lr] = fv.y;
            Fs[kk*4+2][lr] = fv.z; Fs[kk*4+3][lr] = fv.w;
        }
        __syncthreads();
        #pragma unroll 8
        for (int k = 0; k < 64; ++k) {
            float4 a = *(const float4*)&As[k][ty * 4];
            float4 f = *(const float4*)&Fs[k][tx * 4];
            const float aa[4] = {a.x, a.y, a.z, a.w};
            const float ff[4] = {f.x, f.y, f.z, f.w};
            #pragma unroll
            for (int i = 0; i < 4; ++i)
                #pragma unroll
                for (int j = 0; j < 4; ++j)
                    acc[i][j] = fmaf(aa[i], ff[j], acc[i][j]);
        }
        __syncthreads();
    }

    #pragma unroll
    for (int i = 0; i < 4; ++i) {
        const int r = rb + ty * 4 + i;
        f16x4 rv, bv;
        #pragma unroll
        for (int j = 0; j < 4; ++j) {
            const float v = acc[i][j];
            rv[j] = (f16)fmaxf(v, 0.f);
            bv[j] = (v > 0.f) ? (f16)1 : (f16)0;
        }
        f16 *rd, *bd;
        size_t off;
        if (r < Bn) { rd = RX; bd = BX; off = (size_t)r * Fn + cb + tx * 4; }
        else        { rd = RP; bd = BP; off = (size_t)(r - Bn) * Fn + cb + tx * 4; }
        *(f16x4*)(rd + off) = rv;
        *(f16x4*)(bd + off) = bv;
    }
}

// ---------------------------------------------------------------------------
// K2 v7: MFMA for I/X/P, packed VALU only for M.
//  Block = 16b x 16p output tile, 4 waves; wave w owns F-quarter w (128 f).
//  Phase A (MFMA, round-8 validated layouts): per k-step (32 f):
//    A-frag row=l&15, k=(l>>4)*8 from RX/BX; B-frag col=l&15 from RP/BP;
//    aI = mfma(rx,rp,aI); aX = mfma(rx,bp,aX); aP = mfma(bx,rp,aP).
//    C/D: col=l&15, row=(l>>4)*4+i.
//  Phase B (M): lane l covers b_local=l>>2, p_local=(l&3)*4+j (j=0..3);
//    f16x2 min/add accumulators, flushed to f32 every 16 f (v6 cadence).
//  Phase C: LDS combine of 4 wave-partials (deterministic) + ratio.
//  Grid (Bn/16, Pn/16) = 64 x 8 = 512 blocks; LDS 16 KB.
// ---------------------------------------------------------------------------
__global__ __launch_bounds__(256)
void tversky_main(const f16* __restrict__ RX, const f16* __restrict__ BX,
                  const f16* __restrict__ RP, const f16* __restrict__ BP,
                  const float* __restrict__ alpha_p, const float* __restrict__ beta_p,
                  float* __restrict__ out)
{
    __shared__ float sI[4][256], sX[4][256], sP[4][256], sM[4][256];
    const int tid  = threadIdx.x;
    const int w    = tid >> 6;           // wave = F-quarter
    const int lane = tid & 63;
    const int bb   = blockIdx.x * 16;
    const int pb   = blockIdx.y * 16;
    const int f0   = w * 128;

    // ---------------- Phase A: MFMA over F-quarter ----------------
    {
        const size_t abase = (size_t)(bb + (lane & 15)) * Fn + f0 + (lane >> 4) * 8;
        const size_t bbase = (size_t)(pb + (lane & 15)) * Fn + f0 + (lane >> 4) * 8;
        f32x4 aI = {}, aX = {}, aP = {};
        #pragma unroll
        for (int ks = 0; ks < 4; ++ks) {
            const f16x8 rx = *(const f16x8*)(RX + abase + ks * 32);
            const f16x8 bx = *(const f16x8*)(BX + abase + ks * 32);
            const f16x8 rp = *(const f16x8*)(RP + bbase + ks * 32);
            const f16x8 bp = *(const f16x8*)(BP + bbase + ks * 32);
            aI = __builtin_amdgcn_mfma_f32_16x16x32_f16(rx, rp, aI, 0, 0, 0);
            aX = __builtin_amdgcn_mfma_f32_16x16x32_f16(rx, bp, aX, 0, 0, 0);
            aP = __builtin_amdgcn_mfma_f32_16x16x32_f16(bx, rp, aP, 0, 0, 0);
        }
        #pragma unroll
        for (int i = 0; i < 4; ++i) {
            const int idx = ((lane >> 4) * 4 + i) * 16 + (lane & 15);
            sI[w][idx] = aI[i]; sX[w][idx] = aX[i]; sP[w][idx] = aP[i];
        }
    }

    // ---------------- Phase B: M = sum min(rx, rp) over F-quarter ----------
    {
        const int bl = lane >> 2;            // b_local 0..15
        const int pg = lane & 3;             // p-group (4 p's)
        const f16* xrow = RX + (size_t)(bb + bl) * Fn + f0;
        const f16* prow0 = RP + (size_t)(pb + pg * 4) * Fn + f0;

        float fM[4] = {};
        #pragma unroll
        for (int ep = 0; ep < 8; ++ep) {     // 8 epochs x 16 f = 128 f
            f16x2 aM[4] = {};
            #pragma unroll
            for (int gg = 0; gg < 2; ++gg) {
                const int g = ep * 2 + gg;
                const f16x8 rx = *(const f16x8*)(xrow + g * 8);
                #pragma unroll
                for (int j = 0; j < 4; ++j) {
                    const f16x8 rp = *(const f16x8*)(prow0 + (size_t)j * Fn + g * 8);
                    const f16x8 mn = __builtin_elementwise_min(rx, rp);
                    const f16x4 ml = mn.lo, mh = mn.hi;
                    aM[j] = aM[j] + ml.lo;
                    aM[j] = aM[j] + ml.hi;
                    aM[j] = aM[j] + mh.lo;
                    aM[j] = aM[j] + mh.hi;
                }
            }
            #pragma unroll
            for (int j = 0; j < 4; ++j)
                fM[j] += (float)aM[j][0] + (float)aM[j][1];
        }
        #pragma unroll
        for (int j = 0; j < 4; ++j)
            sM[w][bl * 16 + pg * 4 + j] = fM[j];
    }

    __syncthreads();

    // ---------------- Phase C: combine + ratio ----------------
    {
        float I = 0.f, X = 0.f, P = 0.f, M = 0.f;
        #pragma unroll
        for (int s = 0; s < 4; ++s) {
            I += sI[s][tid]; X += sX[s][tid]; P += sP[s][tid]; M += sM[s][tid];
        }
        const float alpha = *alpha_p;
        const float beta  = *beta_p;
        const float W = alpha * (X - M) + beta * (P - M);
        out[(size_t)(bb + (tid >> 4)) * Pn + pb + (tid & 15)] = I / (I + W + THETA);
    }
}

extern "C" void kernel_launch(void* const* d_in, const int* in_sizes, int n_in,
                              void* d_out, int out_size, void* d_ws, size_t ws_size,
                              hipStream_t stream)
{
    const float* x     = (const float*)d_in[0];
    const float* prot  = (const float*)d_in[1];
    const float* fb    = (const float*)d_in[2];
    const float* alpha = (const float*)d_in[3];
    const float* beta  = (const float*)d_in[4];
    float* out = (float*)d_out;

    f16* RX = (f16*)d_ws;                    // Bn*Fn f16
    f16* BX = RX + (size_t)Bn * Fn;          // Bn*Fn f16
    f16* RP = BX + (size_t)Bn * Fn;          // Pn*Fn f16
    f16* BP = RP + (size_t)Pn * Fn;          // Pn*Fn f16

    dim3 gg(Fn / 64, (Bn + Pn) / 64);        // 8 x 18 = 144 blocks
    gemm_feat<<<gg, 256, 0, stream>>>(x, prot, fb, RX, BX, RP, BP);

    dim3 gm(Bn / 16, Pn / 16);               // 64 x 8 = 512 blocks
    tversky_main<<<gm, 256, 0, stream>>>(RX, BX, RP, BP, alpha, beta, out);
}